// Round 1
// baseline (188.387 us; speedup 1.0000x reference)
//
#include <hip/hip_runtime.h>
#include <hip/hip_bf16.h>

#define F_DIM 512
#define H_DIM 256
#define B_DIM 128
#define M_BLK 64
#define K_CHUNK 32
#define K_PAD 40   // 32 + 8 pad: row stride 80B -> bank-uniform b128 access

typedef __bf16 bf16x8 __attribute__((ext_vector_type(8)));
typedef __bf16 bf16x4 __attribute__((ext_vector_type(4)));
typedef float  f32x4  __attribute__((ext_vector_type(4)));

__global__ __launch_bounds__(256) void fused_mlp_r2_kernel(
    const float* __restrict__ pos,
    const float* __restrict__ mass_center,
    const float* __restrict__ scaler,
    const int*   __restrict__ batch_index,
    const float* __restrict__ W1,
    const float* __restrict__ b1,
    const float* __restrict__ W2,
    const float* __restrict__ b2,
    float* __restrict__ out,
    int N)
{
    __shared__ __bf16 A_lds[M_BLK][K_PAD];
    __shared__ __bf16 Bt_lds[H_DIM][K_PAD];   // B transposed: [col][k]
    __shared__ float  q_lds[M_BLK];

    const int tid    = threadIdx.x;
    const int lane   = tid & 63;
    const int wid    = tid >> 6;
    const int wave_m = wid >> 1;   // 0..1 -> 32-row half
    const int wave_n = wid & 1;    // 0..1 -> 128-col half
    const int row_base = blockIdx.x * M_BLK;

    if (tid < M_BLK) q_lds[tid] = 0.0f;

    f32x4 acc[2][8];
    #pragma unroll
    for (int mi = 0; mi < 2; ++mi)
        #pragma unroll
        for (int ni = 0; ni < 8; ++ni)
            acc[mi][ni] = (f32x4){0.f, 0.f, 0.f, 0.f};

    const int lrow = lane & 15;
    const int kq   = (lane >> 4) * 8;   // k offset of this lane's fragment

    for (int kc = 0; kc < F_DIM / K_CHUNK; ++kc) {
        const int k0 = kc * K_CHUNK;
        __syncthreads();   // previous chunk's LDS reads done (also covers q_lds init)

        // ---- stage A: 64 rows x 32 k, f32 -> bf16 ----
        #pragma unroll
        for (int i = 0; i < 2; ++i) {
            int idx  = tid + i * 256;      // 0..511
            int r    = idx >> 3;           // row 0..63
            int f4   = idx & 7;            // which float4 in the 32-wide chunk
            int grow = row_base + r;
            float4 v;
            if (grow < N) v = *(const float4*)&scaler[(size_t)grow * F_DIM + k0 + f4 * 4];
            else          v = make_float4(0.f, 0.f, 0.f, 0.f);
            bf16x4 bv;
            bv.x = (__bf16)v.x; bv.y = (__bf16)v.y; bv.z = (__bf16)v.z; bv.w = (__bf16)v.w;
            *(bf16x4*)&A_lds[r][f4 * 4] = bv;
        }

        // ---- stage B^T: thread t owns column t, 32 k values ----
        {
            bf16x8 pack[4];
            #pragma unroll
            for (int kk = 0; kk < 32; ++kk) {
                float f = W1[(size_t)(k0 + kk) * H_DIM + tid];
                pack[kk >> 3][kk & 7] = (__bf16)f;
            }
            #pragma unroll
            for (int j = 0; j < 4; ++j)
                *(bf16x8*)&Bt_lds[tid][j * 8] = pack[j];
        }

        __syncthreads();

        // ---- fragments + MFMA ----
        bf16x8 afrag[2], bfrag[8];
        #pragma unroll
        for (int mi = 0; mi < 2; ++mi)
            afrag[mi] = *(const bf16x8*)&A_lds[wave_m * 32 + mi * 16 + lrow][kq];
        #pragma unroll
        for (int ni = 0; ni < 8; ++ni)
            bfrag[ni] = *(const bf16x8*)&Bt_lds[wave_n * 128 + ni * 16 + lrow][kq];
        #pragma unroll
        for (int mi = 0; mi < 2; ++mi)
            #pragma unroll
            for (int ni = 0; ni < 8; ++ni)
                acc[mi][ni] = __builtin_amdgcn_mfma_f32_16x16x32_bf16(
                    afrag[mi], bfrag[ni], acc[mi][ni], 0, 0, 0);
    }

    // ---- epilogue: silu + dot(W2), reduce over 16 col-lanes ----
    float qp[2][4];
    #pragma unroll
    for (int mi = 0; mi < 2; ++mi)
        #pragma unroll
        for (int r = 0; r < 4; ++r) qp[mi][r] = 0.f;

    #pragma unroll
    for (int ni = 0; ni < 8; ++ni) {
        int c = wave_n * 128 + ni * 16 + lrow;
        float b1c = b1[c];
        float w2c = W2[c];
        #pragma unroll
        for (int mi = 0; mi < 2; ++mi)
            #pragma unroll
            for (int r = 0; r < 4; ++r) {
                float h = acc[mi][ni][r] + b1c;
                float s = h / (1.0f + __expf(-h));   // silu
                qp[mi][r] += s * w2c;
            }
    }
    #pragma unroll
    for (int off = 1; off < 16; off <<= 1)
        #pragma unroll
        for (int mi = 0; mi < 2; ++mi)
            #pragma unroll
            for (int r = 0; r < 4; ++r)
                qp[mi][r] += __shfl_xor(qp[mi][r], off, 64);

    if ((lane & 15) == 0) {
        int rgrp = lane >> 4;   // 0..3
        #pragma unroll
        for (int mi = 0; mi < 2; ++mi)
            #pragma unroll
            for (int r = 0; r < 4; ++r)
                atomicAdd(&q_lds[wave_m * 32 + mi * 16 + rgrp * 4 + r], qp[mi][r]);
    }
    __syncthreads();

    if (tid < M_BLK) {
        int grow = row_base + tid;
        if (grow < N) {
            float q  = q_lds[tid] + b2[0];
            int   bi = batch_index[grow];
            float dx = pos[grow * 3 + 0] - mass_center[bi * 3 + 0];
            float dy = pos[grow * 3 + 1] - mass_center[bi * 3 + 1];
            float dz = pos[grow * 3 + 2] - mass_center[bi * 3 + 2];
            float r2 = dx * dx + dy * dy + dz * dz;
            atomicAdd(&out[bi], q * r2);
        }
    }
}

extern "C" void kernel_launch(void* const* d_in, const int* in_sizes, int n_in,
                              void* d_out, int out_size, void* d_ws, size_t ws_size,
                              hipStream_t stream) {
    const float* pos         = (const float*)d_in[0];
    const float* mass_center = (const float*)d_in[1];
    const float* scaler      = (const float*)d_in[2];
    // d_in[3] = vector : unused by the reference computation
    const int*   batch_index = (const int*)d_in[4];
    const float* W1          = (const float*)d_in[5];
    const float* b1          = (const float*)d_in[6];
    const float* W2          = (const float*)d_in[7];
    const float* b2          = (const float*)d_in[8];
    float* out = (float*)d_out;
    (void)d_ws; (void)ws_size; (void)n_in; (void)out_size;

    int N = in_sizes[0] / 3;

    hipMemsetAsync(out, 0, B_DIM * sizeof(float), stream);
    int nblk = (N + M_BLK - 1) / M_BLK;
    fused_mlp_r2_kernel<<<nblk, 256, 0, stream>>>(
        pos, mass_center, scaler, batch_index, W1, b1, W2, b2, out, N);
}

// Round 2
// 175.937 us; speedup vs baseline: 1.0708x; 1.0708x over previous
//
#include <hip/hip_runtime.h>
#include <hip/hip_bf16.h>

#define F_DIM 512
#define H_DIM 256
#define B_DIM 128
#define M_BLK 64
#define NCHUNK 16   // 512 / 32

typedef __bf16 bf16x8 __attribute__((ext_vector_type(8)));
typedef float  f32x4  __attribute__((ext_vector_type(4)));

// ---- one-time W1 f32 [K=512][C=256] -> bf16 transposed [C=256][K=512] ----
__global__ __launch_bounds__(256) void convert_w1_kernel(
    const float* __restrict__ W1, __bf16* __restrict__ W1t) {
    int t = blockIdx.x * 256 + threadIdx.x;   // t = c*512 + k
    int c = t >> 9;
    int k = t & 511;
    W1t[t] = (__bf16)W1[k * H_DIM + c];       // coalesced write, cached read
}

// ---- main fused kernel: streaming GEMM (no LDS in K-loop) + silu + W2 + r2 ----
template<bool USE_PARTIAL>
__global__ __launch_bounds__(256) void fused_mlp_kernel(
    const float* __restrict__ pos,
    const float* __restrict__ mass_center,
    const float* __restrict__ scaler,
    const int*   __restrict__ batch_index,
    const __bf16* __restrict__ W1t,
    const float* __restrict__ b1,
    const float* __restrict__ W2,
    const float* __restrict__ b2,
    float* __restrict__ outp,      // USE_PARTIAL ? partial[nblk][128] : out[128]
    int N)
{
    __shared__ float q_lds[M_BLK];
    __shared__ float pb[B_DIM];

    const int tid    = threadIdx.x;
    const int lane   = tid & 63;
    const int wid    = tid >> 6;
    const int wave_m = wid >> 1;     // 0..1 -> 32-row strip
    const int wave_n = wid & 1;      // 0..1 -> 128-col half
    const int lrow   = lane & 15;
    const int kq     = (lane >> 4) * 8;       // k offset of this lane's fragment
    const int row_base = blockIdx.x * M_BLK;

    if (tid < M_BLK) q_lds[tid] = 0.f;
    if (USE_PARTIAL && tid < B_DIM) pb[tid] = 0.f;
    __syncthreads();

    // A pointers (row-clamped for the tail block; bogus rows discarded later)
    const float* aptr[2];
    #pragma unroll
    for (int mi = 0; mi < 2; ++mi) {
        int r = row_base + wave_m * 32 + mi * 16 + lrow;
        if (r >= N) r = N - 1;
        aptr[mi] = scaler + (size_t)r * F_DIM + kq;
    }
    // B pointers (L2-resident bf16 W1t)
    const __bf16* bptr[8];
    #pragma unroll
    for (int ni = 0; ni < 8; ++ni)
        bptr[ni] = W1t + (size_t)(wave_n * 128 + ni * 16 + lrow) * F_DIM + kq;

    f32x4 acc[2][8];
    #pragma unroll
    for (int mi = 0; mi < 2; ++mi)
        #pragma unroll
        for (int ni = 0; ni < 8; ++ni)
            acc[mi][ni] = (f32x4){0.f, 0.f, 0.f, 0.f};

    // register double-buffer for A (f32), one chunk ahead
    f32x4 a_cur[2][2], a_nxt[2][2];
    #pragma unroll
    for (int mi = 0; mi < 2; ++mi)
        #pragma unroll
        for (int h = 0; h < 2; ++h)
            a_cur[mi][h] = *(const f32x4*)(aptr[mi] + h * 4);

    #pragma unroll
    for (int kc = 0; kc < NCHUNK; ++kc) {
        if (kc + 1 < NCHUNK) {
            #pragma unroll
            for (int mi = 0; mi < 2; ++mi)
                #pragma unroll
                for (int h = 0; h < 2; ++h)
                    a_nxt[mi][h] = *(const f32x4*)(aptr[mi] + (kc + 1) * 32 + h * 4);
        }
        // convert current A chunk f32 -> bf16 fragments
        bf16x8 af[2];
        #pragma unroll
        for (int mi = 0; mi < 2; ++mi)
            #pragma unroll
            for (int j = 0; j < 4; ++j) {
                af[mi][j]     = (__bf16)a_cur[mi][0][j];
                af[mi][4 + j] = (__bf16)a_cur[mi][1][j];
            }
        // B fragments straight from L2
        bf16x8 bfv[8];
        #pragma unroll
        for (int ni = 0; ni < 8; ++ni)
            bfv[ni] = *(const bf16x8*)(bptr[ni] + kc * 32);
        #pragma unroll
        for (int mi = 0; mi < 2; ++mi)
            #pragma unroll
            for (int ni = 0; ni < 8; ++ni)
                acc[mi][ni] = __builtin_amdgcn_mfma_f32_16x16x32_bf16(
                    af[mi], bfv[ni], acc[mi][ni], 0, 0, 0);
        #pragma unroll
        for (int mi = 0; mi < 2; ++mi)
            #pragma unroll
            for (int h = 0; h < 2; ++h)
                a_cur[mi][h] = a_nxt[mi][h];
    }

    // ---- epilogue: silu + dot(W2), reduce over the 16 col-lanes ----
    float qp[2][4];
    #pragma unroll
    for (int mi = 0; mi < 2; ++mi)
        #pragma unroll
        for (int r = 0; r < 4; ++r) qp[mi][r] = 0.f;

    #pragma unroll
    for (int ni = 0; ni < 8; ++ni) {
        int c = wave_n * 128 + ni * 16 + lrow;
        float b1c = b1[c];
        float w2c = W2[c];
        #pragma unroll
        for (int mi = 0; mi < 2; ++mi)
            #pragma unroll
            for (int r = 0; r < 4; ++r) {
                float h = acc[mi][ni][r] + b1c;
                float s = h / (1.0f + __expf(-h));
                qp[mi][r] += s * w2c;
            }
    }
    #pragma unroll
    for (int off = 1; off < 16; off <<= 1)
        #pragma unroll
        for (int mi = 0; mi < 2; ++mi)
            #pragma unroll
            for (int r = 0; r < 4; ++r)
                qp[mi][r] += __shfl_xor(qp[mi][r], off, 64);

    if ((lane & 15) == 0) {
        int rgrp = lane >> 4;
        #pragma unroll
        for (int mi = 0; mi < 2; ++mi)
            #pragma unroll
            for (int r = 0; r < 4; ++r)
                atomicAdd(&q_lds[wave_m * 32 + mi * 16 + rgrp * 4 + r], qp[mi][r]);
    }
    __syncthreads();

    if (tid < M_BLK) {
        int grow = row_base + tid;
        if (grow < N) {
            float q  = q_lds[tid] + b2[0];
            int   bi = batch_index[grow];
            float dx = pos[grow * 3 + 0] - mass_center[bi * 3 + 0];
            float dy = pos[grow * 3 + 1] - mass_center[bi * 3 + 1];
            float dz = pos[grow * 3 + 2] - mass_center[bi * 3 + 2];
            float val = q * (dx * dx + dy * dy + dz * dz);
            if (USE_PARTIAL) atomicAdd(&pb[bi], val);
            else             atomicAdd(&outp[bi], val);
        }
    }
    if (USE_PARTIAL) {
        __syncthreads();
        if (tid < B_DIM)
            outp[(size_t)blockIdx.x * B_DIM + tid] = pb[tid];
    }
}

// ---- reduce per-block partials [nblk][128] -> out[128] ----
__global__ __launch_bounds__(256) void reduce_partials_kernel(
    const float* __restrict__ partial, float* __restrict__ out, int nblk) {
    int b = blockIdx.x;
    float s = 0.f;
    for (int i = threadIdx.x; i < nblk; i += 256)
        s += partial[(size_t)i * B_DIM + b];
    #pragma unroll
    for (int off = 1; off < 64; off <<= 1)
        s += __shfl_xor(s, off, 64);
    __shared__ float wsum[4];
    if ((threadIdx.x & 63) == 0) wsum[threadIdx.x >> 6] = s;
    __syncthreads();
    if (threadIdx.x == 0)
        out[b] = wsum[0] + wsum[1] + wsum[2] + wsum[3];
}

extern "C" void kernel_launch(void* const* d_in, const int* in_sizes, int n_in,
                              void* d_out, int out_size, void* d_ws, size_t ws_size,
                              hipStream_t stream) {
    const float* pos         = (const float*)d_in[0];
    const float* mass_center = (const float*)d_in[1];
    const float* scaler      = (const float*)d_in[2];
    // d_in[3] = vector : unused by the reference computation
    const int*   batch_index = (const int*)d_in[4];
    const float* W1          = (const float*)d_in[5];
    const float* b1          = (const float*)d_in[6];
    const float* W2          = (const float*)d_in[7];
    const float* b2          = (const float*)d_in[8];
    float* out = (float*)d_out;
    (void)n_in; (void)out_size;

    int N = in_sizes[0] / 3;
    int nblk = (N + M_BLK - 1) / M_BLK;

    size_t w1t_bytes  = (size_t)F_DIM * H_DIM * sizeof(__bf16);   // 256 KB
    size_t part_bytes = (size_t)nblk * B_DIM * sizeof(float);

    __bf16* W1t = (__bf16*)d_ws;
    convert_w1_kernel<<<(F_DIM * H_DIM) / 256, 256, 0, stream>>>(W1, W1t);

    if (ws_size >= w1t_bytes + part_bytes) {
        float* partial = (float*)((char*)d_ws + w1t_bytes);
        fused_mlp_kernel<true><<<nblk, 256, 0, stream>>>(
            pos, mass_center, scaler, batch_index, W1t, b1, W2, b2, partial, N);
        reduce_partials_kernel<<<B_DIM, 256, 0, stream>>>(partial, out, nblk);
    } else {
        hipMemsetAsync(out, 0, B_DIM * sizeof(float), stream);
        fused_mlp_kernel<false><<<nblk, 256, 0, stream>>>(
            pos, mass_center, scaler, batch_index, W1t, b1, W2, b2, out, N);
    }
}

// Round 3
// 133.800 us; speedup vs baseline: 1.4080x; 1.3149x over previous
//
#include <hip/hip_runtime.h>
#include <hip/hip_bf16.h>
#include <stdint.h>

#define F_DIM 512
#define H_DIM 256
#define B_DIM 128
#define M_BLK 64
#define NCHUNK 16   // 512 / 32

typedef __bf16 bf16x8 __attribute__((ext_vector_type(8)));
typedef float  f32x4  __attribute__((ext_vector_type(4)));

// ---- one-time W1 f32 [K=512][C=256] -> bf16 transposed [C=256][K=512] ----
__global__ __launch_bounds__(256) void convert_w1_kernel(
    const float* __restrict__ W1, __bf16* __restrict__ W1t) {
    int t = blockIdx.x * 256 + threadIdx.x;   // t = c*512 + k
    int c = t >> 9;
    int k = t & 511;
    W1t[t] = (__bf16)W1[k * H_DIM + c];
}

__device__ inline void gload_lds16(const float* g, float* lds) {
    __builtin_amdgcn_global_load_lds(
        (const __attribute__((address_space(1))) uint32_t*)g,
        (__attribute__((address_space(3))) uint32_t*)lds, 16, 0, 0);
}

// ---- main fused kernel ----
// A (f32) staged via async global_load_lds into double-buffered LDS with
// XOR-swizzled source (rule #21: linear dest + inverse-swz source + swz read).
// B (bf16, L2-resident) register-prefetched one chunk ahead.
template<bool USE_PARTIAL>
__global__ __launch_bounds__(512) void fused_mlp_kernel(
    const float* __restrict__ pos,
    const float* __restrict__ mass_center,
    const float* __restrict__ scaler,
    const int*   __restrict__ batch_index,
    const __bf16* __restrict__ W1t,
    const float* __restrict__ b1,
    const float* __restrict__ W2,
    const float* __restrict__ b2,
    float* __restrict__ outp,
    int N)
{
    __shared__ float A_lds[2][M_BLK][32];   // 2 x 8 KB
    __shared__ float q_lds[M_BLK];
    __shared__ float pb[B_DIM];

    const int tid    = threadIdx.x;
    const int lane   = tid & 63;
    const int wid    = tid >> 6;     // 0..7
    const int wave_m = wid & 1;      // 2 strips of 32 rows
    const int wave_n = wid >> 1;     // 4 strips of 64 cols
    const int lrow   = lane & 15;
    const int kq     = (lane >> 4) * 8;     // k-elem offset of this lane's fragment
    const int row_base = blockIdx.x * M_BLK;

    if (tid < M_BLK) q_lds[tid] = 0.f;
    if (USE_PARTIAL && tid < B_DIM) pb[tid] = 0.f;

    // staging: thread t -> LDS row t>>3, 16B slot t&7 (linear dest),
    // global seg pre-swizzled: seg = (t&7) ^ (row&7)
    const int srow = tid >> 3;
    const int sseg = (tid & 7) ^ (srow & 7);
    int g_row = row_base + srow; if (g_row >= N) g_row = N - 1;
    const float* g_src = scaler + (size_t)g_row * F_DIM + sseg * 4;
    float* lds_dst0 = &A_lds[0][wid * 8][0];   // wave-uniform base (+lane*16 by HW)
    float* lds_dst1 = &A_lds[1][wid * 8][0];

    // B pointers (bf16 W1t [col][k])
    const __bf16* bptr[4];
    #pragma unroll
    for (int ni = 0; ni < 4; ++ni)
        bptr[ni] = W1t + (size_t)(wave_n * 64 + ni * 16 + lrow) * F_DIM + kq;

    f32x4 acc[2][4];
    #pragma unroll
    for (int mi = 0; mi < 2; ++mi)
        #pragma unroll
        for (int ni = 0; ni < 4; ++ni)
            acc[mi][ni] = (f32x4){0.f, 0.f, 0.f, 0.f};

    // prologue: stage chunk 0, load B(0)
    gload_lds16(g_src, lds_dst0);
    bf16x8 bcur[4], bnxt[4];
    #pragma unroll
    for (int ni = 0; ni < 4; ++ni)
        bcur[ni] = *(const bf16x8*)(bptr[ni]);
    __syncthreads();   // drains stage(0); fences q_lds/pb init

    #pragma unroll
    for (int kc = 0; kc < NCHUNK; ++kc) {
        // issue next chunk's stage + B prefetch BEFORE compute: the compiler's
        // wait on bcur is then a counted vmcnt that keeps these in flight
        if (kc + 1 < NCHUNK) {
            gload_lds16(g_src + (kc + 1) * 32, (kc & 1) ? lds_dst0 : lds_dst1);
            #pragma unroll
            for (int ni = 0; ni < 4; ++ni)
                bnxt[ni] = *(const bf16x8*)(bptr[ni] + (kc + 1) * 32);
        }
        // compute chunk kc from buf kc&1
        const char* abase = (const char*)&A_lds[kc & 1][0][0];
        bf16x8 af[2];
        #pragma unroll
        for (int mi = 0; mi < 2; ++mi) {
            const int rA = wave_m * 32 + mi * 16 + lrow;
            const int sw = (rA & 7) << 4;
            const char* rb = abase + rA * 128;
            f32x4 a0 = *(const f32x4*)(rb + ((kq * 4) ^ sw));
            f32x4 a1 = *(const f32x4*)(rb + ((kq * 4 + 16) ^ sw));
            #pragma unroll
            for (int j = 0; j < 4; ++j) {
                af[mi][j]     = (__bf16)a0[j];
                af[mi][4 + j] = (__bf16)a1[j];
            }
        }
        #pragma unroll
        for (int mi = 0; mi < 2; ++mi)
            #pragma unroll
            for (int ni = 0; ni < 4; ++ni)
                acc[mi][ni] = __builtin_amdgcn_mfma_f32_16x16x32_bf16(
                    af[mi], bcur[ni], acc[mi][ni], 0, 0, 0);
        __syncthreads();   // readers done with buf (kc&1) + drain next stage
        #pragma unroll
        for (int ni = 0; ni < 4; ++ni)
            bcur[ni] = bnxt[ni];
    }

    // ---- epilogue: silu + dot(W2), reduce over the 16 col-lanes ----
    float qp[2][4];
    #pragma unroll
    for (int mi = 0; mi < 2; ++mi)
        #pragma unroll
        for (int r = 0; r < 4; ++r) qp[mi][r] = 0.f;

    #pragma unroll
    for (int ni = 0; ni < 4; ++ni) {
        int c = wave_n * 64 + ni * 16 + lrow;
        float b1c = b1[c];
        float w2c = W2[c];
        #pragma unroll
        for (int mi = 0; mi < 2; ++mi)
            #pragma unroll
            for (int r = 0; r < 4; ++r) {
                float h = acc[mi][ni][r] + b1c;
                float s = h / (1.0f + __expf(-h));
                qp[mi][r] += s * w2c;
            }
    }
    #pragma unroll
    for (int off = 1; off < 16; off <<= 1)
        #pragma unroll
        for (int mi = 0; mi < 2; ++mi)
            #pragma unroll
            for (int r = 0; r < 4; ++r)
                qp[mi][r] += __shfl_xor(qp[mi][r], off, 64);

    if ((lane & 15) == 0) {
        int rgrp = lane >> 4;
        #pragma unroll
        for (int mi = 0; mi < 2; ++mi)
            #pragma unroll
            for (int r = 0; r < 4; ++r)
                atomicAdd(&q_lds[wave_m * 32 + mi * 16 + rgrp * 4 + r], qp[mi][r]);
    }
    __syncthreads();

    if (tid < M_BLK) {
        int grow = row_base + tid;
        if (grow < N) {
            float q  = q_lds[tid] + b2[0];
            int   bi = batch_index[grow];
            float dx = pos[grow * 3 + 0] - mass_center[bi * 3 + 0];
            float dy = pos[grow * 3 + 1] - mass_center[bi * 3 + 1];
            float dz = pos[grow * 3 + 2] - mass_center[bi * 3 + 2];
            float val = q * (dx * dx + dy * dy + dz * dz);
            if (USE_PARTIAL) atomicAdd(&pb[bi], val);
            else             atomicAdd(&outp[bi], val);
        }
    }
    if (USE_PARTIAL) {
        __syncthreads();
        if (tid < B_DIM)
            outp[(size_t)blockIdx.x * B_DIM + tid] = pb[tid];
    }
}

// ---- reduce per-block partials [nblk][128] -> out[128] ----
__global__ __launch_bounds__(256) void reduce_partials_kernel(
    const float* __restrict__ partial, float* __restrict__ out, int nblk) {
    int b = blockIdx.x;
    float s = 0.f;
    for (int i = threadIdx.x; i < nblk; i += 256)
        s += partial[(size_t)i * B_DIM + b];
    #pragma unroll
    for (int off = 1; off < 64; off <<= 1)
        s += __shfl_xor(s, off, 64);
    __shared__ float wsum[4];
    if ((threadIdx.x & 63) == 0) wsum[threadIdx.x >> 6] = s;
    __syncthreads();
    if (threadIdx.x == 0)
        out[b] = wsum[0] + wsum[1] + wsum[2] + wsum[3];
}

extern "C" void kernel_launch(void* const* d_in, const int* in_sizes, int n_in,
                              void* d_out, int out_size, void* d_ws, size_t ws_size,
                              hipStream_t stream) {
    const float* pos         = (const float*)d_in[0];
    const float* mass_center = (const float*)d_in[1];
    const float* scaler      = (const float*)d_in[2];
    // d_in[3] = vector : unused by the reference computation
    const int*   batch_index = (const int*)d_in[4];
    const float* W1          = (const float*)d_in[5];
    const float* b1          = (const float*)d_in[6];
    const float* W2          = (const float*)d_in[7];
    const float* b2          = (const float*)d_in[8];
    float* out = (float*)d_out;
    (void)n_in; (void)out_size;

    int N = in_sizes[0] / 3;
    int nblk = (N + M_BLK - 1) / M_BLK;

    size_t w1t_bytes  = (size_t)F_DIM * H_DIM * sizeof(__bf16);   // 256 KB
    size_t part_bytes = (size_t)nblk * B_DIM * sizeof(float);

    __bf16* W1t = (__bf16*)d_ws;
    convert_w1_kernel<<<(F_DIM * H_DIM) / 256, 256, 0, stream>>>(W1, W1t);

    if (ws_size >= w1t_bytes + part_bytes) {
        float* partial = (float*)((char*)d_ws + w1t_bytes);
        fused_mlp_kernel<true><<<nblk, 512, 0, stream>>>(
            pos, mass_center, scaler, batch_index, W1t, b1, W2, b2, partial, N);
        reduce_partials_kernel<<<B_DIM, 256, 0, stream>>>(partial, out, nblk);
    } else {
        hipMemsetAsync(out, 0, B_DIM * sizeof(float), stream);
        fused_mlp_kernel<false><<<nblk, 512, 0, stream>>>(
            pos, mass_center, scaler, batch_index, W1t, b1, W2, b2, out, N);
    }
}

// Round 4
// 122.247 us; speedup vs baseline: 1.5410x; 1.0945x over previous
//
#include <hip/hip_runtime.h>
#include <hip/hip_bf16.h>
#include <stdint.h>

#define F_DIM 512
#define H_DIM 256
#define B_DIM 128
#define M_BLK 128
#define NCHUNK 16   // 512 / 32
#define NBUF 3

typedef __bf16 bf16x8 __attribute__((ext_vector_type(8)));
typedef float  f32x4  __attribute__((ext_vector_type(4)));

// ---- one-time W1 f32 [K=512][C=256] -> bf16 transposed [C=256][K=512] ----
__global__ __launch_bounds__(256) void convert_w1_kernel(
    const float* __restrict__ W1, __bf16* __restrict__ W1t) {
    int t = blockIdx.x * 256 + threadIdx.x;   // t = c*512 + k
    int c = t >> 9;
    int k = t & 511;
    W1t[t] = (__bf16)W1[k * H_DIM + c];
}

__device__ inline void gload_lds16(const float* g, float* lds) {
    __builtin_amdgcn_global_load_lds(
        (const __attribute__((address_space(1))) uint32_t*)g,
        (__attribute__((address_space(3))) uint32_t*)lds, 16, 0, 0);
}

// ---- main fused kernel: T3/T4 counted-vmcnt pipeline ----
// A (f32) staged depth-3 via global_load_lds (XOR-swizzled source + swizzled
// read, linear LDS dest). B (bf16, L2-resident) register-prefetched 1 ahead.
// Raw s_barrier + counted vmcnt: stages stay in flight across barriers.
template<bool USE_PARTIAL>
__global__ __launch_bounds__(512) void fused_mlp_kernel(
    const float* __restrict__ pos,
    const float* __restrict__ mass_center,
    const float* __restrict__ scaler,
    const int*   __restrict__ batch_index,
    const __bf16* __restrict__ W1t,
    const float* __restrict__ b1,
    const float* __restrict__ W2,
    const float* __restrict__ b2,
    float* __restrict__ outp,
    int N)
{
    __shared__ float A_lds[NBUF][M_BLK][32];   // 3 x 16 KB
    __shared__ float q_lds[M_BLK];
    __shared__ float pb[B_DIM];

    const int tid    = threadIdx.x;
    const int lane   = tid & 63;
    const int wid    = tid >> 6;     // 0..7
    const int wave_m = wid & 1;      // 2 strips of 64 rows
    const int wave_n = wid >> 1;     // 4 strips of 64 cols
    const int lrow   = lane & 15;
    const int kq     = (lane >> 4) * 8;     // k-elem offset of this lane's fragment
    const int row_base = blockIdx.x * M_BLK;

    if (tid < M_BLK) q_lds[tid] = 0.f;
    if (USE_PARTIAL && tid < B_DIM) pb[tid] = 0.f;

    // staging: thread t covers 16B slots {t, t+512}; slot s -> row s>>3, seg s&7
    // (linear LDS dest; source seg pre-swizzled by row so reads can XOR-unswizzle)
    const int srow0 = tid >> 3;
    const int sseg0 = (tid & 7) ^ (srow0 & 7);
    const int srow1 = (tid + 512) >> 3;
    const int sseg1 = ((tid + 512) & 7) ^ (srow1 & 7);
    int gr0 = row_base + srow0; if (gr0 >= N) gr0 = N - 1;
    int gr1 = row_base + srow1; if (gr1 >= N) gr1 = N - 1;
    const float* gs0 = scaler + (size_t)gr0 * F_DIM + sseg0 * 4;
    const float* gs1 = scaler + (size_t)gr1 * F_DIM + sseg1 * 4;

#define STAGE(buf, c) do {                                          \
        gload_lds16(gs0 + (c) * 32, &A_lds[(buf)][0][0]  + wid * 256); \
        gload_lds16(gs1 + (c) * 32, &A_lds[(buf)][64][0] + wid * 256); \
    } while (0)

    // B pointers (bf16 W1t [col][k])
    const __bf16* bptr[4];
    #pragma unroll
    for (int ni = 0; ni < 4; ++ni)
        bptr[ni] = W1t + (size_t)(wave_n * 64 + ni * 16 + lrow) * F_DIM + kq;

    f32x4 acc[4][4];
    #pragma unroll
    for (int mi = 0; mi < 4; ++mi)
        #pragma unroll
        for (int ni = 0; ni < 4; ++ni)
            acc[mi][ni] = (f32x4){0.f, 0.f, 0.f, 0.f};

    // prologue: B(0), stage(0), stage(1)  [issue order matters for vmcnt counts]
    bf16x8 bcur[4], bnxt[4];
    #pragma unroll
    for (int ni = 0; ni < 4; ++ni)
        bcur[ni] = *(const bf16x8*)(bptr[ni]);
    STAGE(0, 0);
    STAGE(1, 1);

    #pragma unroll
    for (int kc = 0; kc < NCHUNK; ++kc) {
        // per-iteration issues: exactly 4 B-loads + 2 global_load_lds (steady)
        if (kc + 1 < NCHUNK) {
            #pragma unroll
            for (int ni = 0; ni < 4; ++ni)
                bnxt[ni] = *(const bf16x8*)(bptr[ni] + (kc + 1) * 32);
        }
        if (kc + 2 < NCHUNK)
            STAGE((kc + 2) % NBUF, kc + 2);

        // counted wait: stage(kc) complete; stage(kc+1), stage(kc+2), B(kc+1)
        // stay in flight across the barrier (the whole point).
        if (kc < NCHUNK - 2)      asm volatile("s_waitcnt vmcnt(8)" ::: "memory");
        else if (kc == NCHUNK - 2) asm volatile("s_waitcnt vmcnt(6)" ::: "memory");
        else                       asm volatile("s_waitcnt vmcnt(0)" ::: "memory");
        __builtin_amdgcn_s_barrier();

        // compute chunk kc from buf kc%3
        const char* abase = (const char*)&A_lds[kc % NBUF][0][0];
        bf16x8 af[4];
        #pragma unroll
        for (int mi = 0; mi < 4; ++mi) {
            const int rA = wave_m * 64 + mi * 16 + lrow;
            const int sw = (rA & 7) << 4;
            const char* rb = abase + rA * 128;
            f32x4 a0 = *(const f32x4*)(rb + ((kq * 4) ^ sw));
            f32x4 a1 = *(const f32x4*)(rb + ((kq * 4 + 16) ^ sw));
            #pragma unroll
            for (int j = 0; j < 4; ++j) {
                af[mi][j]     = (__bf16)a0[j];
                af[mi][4 + j] = (__bf16)a1[j];
            }
        }
        #pragma unroll
        for (int mi = 0; mi < 4; ++mi)
            #pragma unroll
            for (int ni = 0; ni < 4; ++ni)
                acc[mi][ni] = __builtin_amdgcn_mfma_f32_16x16x32_bf16(
                    af[mi], bcur[ni], acc[mi][ni], 0, 0, 0);

        __builtin_amdgcn_s_barrier();   // readers done before buf reuse
        #pragma unroll
        for (int ni = 0; ni < 4; ++ni)
            bcur[ni] = bnxt[ni];
    }
#undef STAGE

    // ---- epilogue: silu + dot(W2), reduce over the 16 col-lanes ----
    float qp[4][4];
    #pragma unroll
    for (int mi = 0; mi < 4; ++mi)
        #pragma unroll
        for (int r = 0; r < 4; ++r) qp[mi][r] = 0.f;

    #pragma unroll
    for (int ni = 0; ni < 4; ++ni) {
        int c = wave_n * 64 + ni * 16 + lrow;
        float b1c = b1[c];
        float w2c = W2[c];
        #pragma unroll
        for (int mi = 0; mi < 4; ++mi)
            #pragma unroll
            for (int r = 0; r < 4; ++r) {
                float h = acc[mi][ni][r] + b1c;
                float s = h / (1.0f + __expf(-h));
                qp[mi][r] += s * w2c;
            }
    }
    #pragma unroll
    for (int off = 1; off < 16; off <<= 1)
        #pragma unroll
        for (int mi = 0; mi < 4; ++mi)
            #pragma unroll
            for (int r = 0; r < 4; ++r)
                qp[mi][r] += __shfl_xor(qp[mi][r], off, 64);

    if ((lane & 15) == 0) {
        int rgrp = lane >> 4;
        #pragma unroll
        for (int mi = 0; mi < 4; ++mi)
            #pragma unroll
            for (int r = 0; r < 4; ++r)
                atomicAdd(&q_lds[wave_m * 64 + mi * 16 + rgrp * 4 + r], qp[mi][r]);
    }
    __syncthreads();

    if (tid < M_BLK) {
        int grow = row_base + tid;
        if (grow < N) {
            float q  = q_lds[tid] + b2[0];
            int   bi = batch_index[grow];
            float dx = pos[grow * 3 + 0] - mass_center[bi * 3 + 0];
            float dy = pos[grow * 3 + 1] - mass_center[bi * 3 + 1];
            float dz = pos[grow * 3 + 2] - mass_center[bi * 3 + 2];
            float val = q * (dx * dx + dy * dy + dz * dz);
            if (USE_PARTIAL) atomicAdd(&pb[bi], val);
            else             atomicAdd(&outp[bi], val);
        }
    }
    if (USE_PARTIAL) {
        __syncthreads();
        if (tid < B_DIM)
            outp[(size_t)blockIdx.x * B_DIM + tid] = pb[tid];
    }
}

// ---- reduce per-block partials [nblk][128] -> out[128] ----
__global__ __launch_bounds__(256) void reduce_partials_kernel(
    const float* __restrict__ partial, float* __restrict__ out, int nblk) {
    int b = blockIdx.x;
    float s = 0.f;
    for (int i = threadIdx.x; i < nblk; i += 256)
        s += partial[(size_t)i * B_DIM + b];
    #pragma unroll
    for (int off = 1; off < 64; off <<= 1)
        s += __shfl_xor(s, off, 64);
    __shared__ float wsum[4];
    if ((threadIdx.x & 63) == 0) wsum[threadIdx.x >> 6] = s;
    __syncthreads();
    if (threadIdx.x == 0)
        out[b] = wsum[0] + wsum[1] + wsum[2] + wsum[3];
}

extern "C" void kernel_launch(void* const* d_in, const int* in_sizes, int n_in,
                              void* d_out, int out_size, void* d_ws, size_t ws_size,
                              hipStream_t stream) {
    const float* pos         = (const float*)d_in[0];
    const float* mass_center = (const float*)d_in[1];
    const float* scaler      = (const float*)d_in[2];
    // d_in[3] = vector : unused by the reference computation
    const int*   batch_index = (const int*)d_in[4];
    const float* W1          = (const float*)d_in[5];
    const float* b1          = (const float*)d_in[6];
    const float* W2          = (const float*)d_in[7];
    const float* b2          = (const float*)d_in[8];
    float* out = (float*)d_out;
    (void)n_in; (void)out_size;

    int N = in_sizes[0] / 3;
    int nblk = (N + M_BLK - 1) / M_BLK;

    size_t w1t_bytes  = (size_t)F_DIM * H_DIM * sizeof(__bf16);   // 256 KB
    size_t part_bytes = (size_t)nblk * B_DIM * sizeof(float);

    __bf16* W1t = (__bf16*)d_ws;
    convert_w1_kernel<<<(F_DIM * H_DIM) / 256, 256, 0, stream>>>(W1, W1t);

    if (ws_size >= w1t_bytes + part_bytes) {
        float* partial = (float*)((char*)d_ws + w1t_bytes);
        fused_mlp_kernel<true><<<nblk, 512, 0, stream>>>(
            pos, mass_center, scaler, batch_index, W1t, b1, W2, b2, partial, N);
        reduce_partials_kernel<<<B_DIM, 256, 0, stream>>>(partial, out, nblk);
    } else {
        hipMemsetAsync(out, 0, B_DIM * sizeof(float), stream);
        fused_mlp_kernel<false><<<nblk, 512, 0, stream>>>(
            pos, mass_center, scaler, batch_index, W1t, b1, W2, b2, out, N);
    }
}